// Round 6
// baseline (948.179 us; speedup 1.0000x reference)
//
#include <hip/hip_runtime.h>
#include <stdint.h>

// CAN_Layer reduces exactly to: out[:, :2048] = out[:, 2048:] =
//   0.5 * (protein @ Wv_p + drug @ Wv_d)
// (seq-len 1 -> softmax over singleton axis == 1 -> attention = identity on V).
//
// R6: cast_a pass DELETED — fp32->bf16 A-cast fused into gemm8's staging
// (reg-staged: coalesced fp32 loads issued 2 phases early, pack_bf16x2,
// ds_write_b64 to the swizzled LDS address; global source row-linear).
// gemm8 skeleton = R3's fastest-verified 2-barrier quadrant schedule.
// B staging unchanged: pre-swizzled global src + linear global_load_lds.
// Ledger: compiler's vmcnt wait before each A-pack retires the earlier-
// issued B halves (in-order retirement) -> no explicit VMW in main loop.

typedef __attribute__((ext_vector_type(8))) short short8;
typedef __attribute__((ext_vector_type(4))) float float4v;
typedef __attribute__((ext_vector_type(2))) unsigned int uint2v;

typedef const __attribute__((address_space(1))) unsigned int* gp_t;
typedef __attribute__((address_space(3))) unsigned int* lp_t;

#define M_DIM 16384
#define N_DIM 2048
#define K_DIM 4096
#define OUT_LD 4096

static __device__ __forceinline__ unsigned int pack_bf16x2(float x, float y) {
  union { float f; unsigned int u; } a, b;
  a.f = x; b.f = y;
  unsigned int ua = a.u + 0x8000u;
  unsigned int ub = b.u + 0x8000u;
  return __builtin_amdgcn_perm(ub, ua, 0x07060302u);
}

static __device__ __forceinline__ unsigned short f2bf(float x) {
  union { float f; unsigned int u; } a; a.f = x;
  return (unsigned short)((a.u + 0x8000u) >> 16);
}

// ---- Pass 1a: Wt[n][k] = bf16(W[k][n]), W = Wv_p (k<2048) else Wv_d ----
__global__ __launch_bounds__(256)
void prep_wt(const float* __restrict__ Wp, const float* __restrict__ Wd,
             unsigned short* __restrict__ Wt) {
  __shared__ float tile[32][33];
  const int k0 = blockIdx.x * 32;
  const int n0 = blockIdx.y * 32;
  const int tx = threadIdx.x;
  const int ty = threadIdx.y;
  const float* W = (k0 < 2048) ? Wp : Wd;
  const int kk0 = (k0 < 2048) ? k0 : k0 - 2048;
#pragma unroll
  for (int i = 0; i < 4; ++i) {
    int r = ty * 4 + i;
    tile[r][tx] = W[(size_t)(kk0 + r) * 2048 + n0 + tx];
  }
  __syncthreads();
#pragma unroll
  for (int i = 0; i < 4; ++i) {
    int r = ty * 4 + i;
    Wt[(size_t)(n0 + r) * (size_t)K_DIM + k0 + tx] = f2bf(tile[tx][r]);
  }
}

// =====================================================================
// Pass 2: 256x256 tile, BK=64, 8 waves (2x4), R3 quadrant schedule.
// Phase ledger (tile tt, buf=tt&1, k2=(tt+2)*64, k3=(tt+3)*64):
//  P0: dsread af(H0) + b0r | BAR LGW0 MFMA(0,0) BAR
//  P1: dsread b1r | issue vA1(tt+2,H1) | packwrite A0(tt+2)<-vA0 |
//      gll B0(tt+2) | BAR LGW0 MFMA(0,1) BAR
//  P2: dsread af(H1) | gll B1(tt+2) | BAR LGW0 MFMA(1,1) BAR
//  P3: packwrite A1(tt+2)<-vA1 | issue vA0(tt+3,H0) | BAR LGW0 MFMA(1,0) BAR
// Overwrite safety: A0 region last read P0 (drain P0-LGW0, publish P0
// end-BAR) -> written P1. A1: read P2 -> written P3. B0: read P0 -> staged
// P1. B1: read P1 -> staged P2. ds_writes drain at same phase's mid-LGW0,
// >=1 barrier before readers. B vmcnt cover: pack of vA0 at tt P1 waits a
// load issued tt-1 P3 > B1(tt+1) issued tt-1 P2 -> retires all B(tt+1)
// before its reads at tt+1 P0/P1 (in-order vmcnt retirement).
// =====================================================================

#define VMW(N) asm volatile("s_waitcnt vmcnt(" #N ")" ::: "memory")
#define LGW0() asm volatile("s_waitcnt lgkmcnt(0)" ::: "memory")
#define BAR() __builtin_amdgcn_s_barrier()
#define SP1 __builtin_amdgcn_s_setprio(1);
#define SP0 __builtin_amdgcn_s_setprio(0);

#define LOAD_A(Ac, QM)                                                      \
  _Pragma("unroll") for (int i = 0; i < 4; ++i) {                           \
    af[i][0] = *(const short8*)&(Ac)[aoff + ((QM)*4 + i) * 1024 + c0];      \
    af[i][1] = *(const short8*)&(Ac)[aoff + ((QM)*4 + i) * 1024 + c1];      \
  }

#define LOAD_B2(dst, Bc, QN)                                                \
  _Pragma("unroll") for (int j = 0; j < 2; ++j) {                           \
    dst[j][0] = *(const short8*)&(Bc)[boff + ((QN)*2 + j) * 1024 + c0];     \
    dst[j][1] = *(const short8*)&(Bc)[boff + ((QN)*2 + j) * 1024 + c1];     \
  }

#define MFMA_Q(bset, QM, QN)                                                \
  _Pragma("unroll") for (int i = 0; i < 4; ++i)                             \
  _Pragma("unroll") for (int j = 0; j < 2; ++j) {                           \
    acc[(QM)*4 + i][(QN)*2 + j] = __builtin_amdgcn_mfma_f32_16x16x32_bf16(  \
        af[i][0], bset[j][0], acc[(QM)*4 + i][(QN)*2 + j], 0, 0, 0);        \
    acc[(QM)*4 + i][(QN)*2 + j] = __builtin_amdgcn_mfma_f32_16x16x32_bf16(  \
        af[i][1], bset[j][1], acc[(QM)*4 + i][(QN)*2 + j], 0, 0, 0);        \
  }

__global__ __launch_bounds__(512, 2)
void gemm8(const float* __restrict__ Pp, const float* __restrict__ Dd,
           const unsigned short* __restrict__ Wt,
           float* __restrict__ out) {
  __shared__ unsigned short As[2][256 * 64];  // 64 KB
  __shared__ unsigned short Bs[2][256 * 64];  // 64 KB

  const int t = threadIdx.x;
  const int w = t >> 6, l = t & 63;
  const int wm = w >> 2, wn = w & 3;          // 2x4 wave grid
  const int lr = l & 15, q16 = l >> 4, xr = lr & 7;

  // Chunked XCD swizzle: XCD (bx&7) owns contiguous logical [x*64,(x+1)*64)
  const int bx = blockIdx.x;                  // 512 blocks
  const int logical = (bx & 7) * 64 + (bx >> 3);
  const int tn = logical & 7, tm = logical >> 3;
  const int m0 = tm << 8, n0 = tn << 8;

  // B staging (global_load_lds, pre-swizzled source, linear LDS dest)
  const int srow = t >> 3;
  const int sk = (((t & 7) ^ (srow & 7)) << 3);
  const int brr = srow & 31;
  const int bsel = t >> 8;

  auto stage_b = [&](int buf, int k0, int nh) {
#pragma unroll
    for (int sub = 0; sub < 2; ++sub) {
      const int wnr = sub * 2 + bsel;
      const int ncol = n0 + wnr * 64 + nh * 32 + brr;
      const unsigned short* g = Wt + (size_t)ncol * K_DIM + (k0 + sk);
      const int ldsrow0 = wnr * 64 + nh * 32 + ((w & 3) << 3);
      __builtin_amdgcn_global_load_lds((gp_t)(const void*)g,
                                       (lp_t)&Bs[buf][ldsrow0 * 64], 16, 0, 0);
    }
  };

  // A staging (reg-staged fused cast): sweep s covers rows s*32+(t>>4),
  // float cols (t&15)*4..+3; per half: 4 dwordx4 + 8 packs + 4 ds_write_b64.
  const int s_r = t >> 4;           // 0..31
  const int s_c = (t & 15) * 4;     // float col 0..60

  auto loadA = [&](float4v* v, int h, int k0) {
    const float* base; int kk;
    if (k0 < 2048) { base = Pp; kk = k0; } else { base = Dd; kk = k0 - 2048; }
#pragma unroll
    for (int s = 0; s < 4; ++s) {
      const int rh = s * 32 + s_r;  // 0..127 within half
      const int row = m0 + (rh >> 6) * 128 + h * 64 + (rh & 63);
      v[s] = *(const float4v*)(base + (size_t)row * 2048 + kk + s_c);
    }
  };
  auto writeA = [&](int buf, int h, const float4v* v) {
#pragma unroll
    for (int s = 0; s < 4; ++s) {
      const int rh = s * 32 + s_r;
      const int row_lds = (rh >> 6) * 128 + h * 64 + (rh & 63);
      const int col_sw = (((s_c >> 3) ^ (rh & 7)) << 3) + (s_c & 7);
      uint2v u;
      u.x = pack_bf16x2(v[s].x, v[s].y);
      u.y = pack_bf16x2(v[s].z, v[s].w);
      *(uint2v*)&As[buf][row_lds * 64 + col_sw] = u;
    }
  };

  float4v acc[8][4];
#pragma unroll
  for (int i = 0; i < 8; ++i)
#pragma unroll
    for (int j = 0; j < 4; ++j)
      acc[i][j] = (float4v){0.f, 0.f, 0.f, 0.f};

  // compute-side ds_read addressing (swizzled), unchanged from R3
  const int aoff = (wm * 128 + lr) * 64;
  const int boff = (wn * 64 + lr) * 64;
  const int c0 = (q16 ^ xr) << 3;            // ks = 0
  const int c1 = ((4 + q16) ^ xr) << 3;      // ks = 1

  float4v vA0[4], vA1[4];

  // ---- prologue: A tiles 0,1 (load+pack+write), B tiles 0,1 (gll),
  //      issue vA0(tile2 H0); VMW(4) retires all 8 B; drain writes; BAR.
  {
    float4v vT[4];
#pragma unroll
    for (int q = 0; q < 2; ++q)
#pragma unroll
      for (int h = 0; h < 2; ++h) {
        loadA(vT, h, q * 64);
        writeA(q, h, vT);
      }
  }
  stage_b(0, 0, 0);
  stage_b(0, 0, 1);
  stage_b(1, 64, 0);
  stage_b(1, 64, 1);
  loadA(vA0, 0, 128);
  VMW(4);
  LGW0();
  BAR();

  // ---- main loop: tiles 0..61 (62,63 in epilogue) ----
  short8 af[4][2];
  short8 b0r[2][2];
  short8 b1r[2][2];
  for (int tt = 0; tt < 62; ++tt) {
    const int buf = tt & 1;
    unsigned short* Ac = &As[buf][0];
    unsigned short* Bc = &Bs[buf][0];
    const int k2 = tt * 64 + 128;                  // tile tt+2
    const int k3 = (tt < 61) ? tt * 64 + 192 : 0;  // tile tt+3 (guarded)

    // P0: (0,0)
    LOAD_A(Ac, 0)
    LOAD_B2(b0r, Bc, 0)
    BAR(); LGW0();
    SP1 MFMA_Q(b0r, 0, 0) SP0
    BAR();

    // P1: (0,1); issue vA1(tt+2,H1); packwrite A0(tt+2); stage B0(tt+2)
    LOAD_B2(b1r, Bc, 1)
    loadA(vA1, 1, k2);
    writeA(buf, 0, vA0);
    stage_b(buf, k2, 0);
    BAR(); LGW0();
    SP1 MFMA_Q(b1r, 0, 1) SP0
    BAR();

    // P2: (1,1); stage B1(tt+2)
    LOAD_A(Ac, 1)
    stage_b(buf, k2, 1);
    BAR(); LGW0();
    SP1 MFMA_Q(b1r, 1, 1) SP0
    BAR();

    // P3: (1,0); packwrite A1(tt+2); issue vA0(tt+3,H0)
    writeA(buf, 1, vA1);
    loadA(vA0, 0, k3);
    BAR(); LGW0();
    SP1 MFMA_Q(b0r, 1, 0) SP0
    BAR();
  }

  // ---- epilogue: drain everything, compute tiles 62 (buf0), 63 (buf1) ----
  VMW(0);
  LGW0();
  BAR();
#pragma unroll
  for (int e = 0; e < 2; ++e) {
    unsigned short* Ac = &As[e][0];
    unsigned short* Bc = &Bs[e][0];
    SP1
    LOAD_A(Ac, 0)
    LOAD_B2(b0r, Bc, 0)
    MFMA_Q(b0r, 0, 0)
    LOAD_B2(b1r, Bc, 1)
    MFMA_Q(b1r, 0, 1)
    LOAD_A(Ac, 1)
    MFMA_Q(b1r, 1, 1)
    MFMA_Q(b0r, 1, 0)
    SP0
  }

  // ---- C write: col = lane&15, row = (lane>>4)*4 + reg; both output halves
  const int rbase = m0 + wm * 128 + q16 * 4;
  const int cbase = n0 + wn * 64 + lr;
#pragma unroll
  for (int f = 0; f < 8; ++f)
#pragma unroll
    for (int j = 0; j < 4; ++j) {
      const int row = rbase + f * 16;
      const int col = cbase + j * 16;
#pragma unroll
      for (int r = 0; r < 4; ++r) {
        float v = acc[f][j][r] * 0.5f;
        size_t o = (size_t)(row + r) * (size_t)OUT_LD + col;
        out[o] = v;
        out[o + N_DIM] = v;
      }
    }
}

// ---- insurance fallback (no usable ws): fp32 LDS-tiled vector GEMM ----
__global__ __launch_bounds__(256)
void gemm_fallback(const float* __restrict__ P, const float* __restrict__ Dg,
                   const float* __restrict__ Wp, const float* __restrict__ Wd,
                   float* __restrict__ out) {
  __shared__ float Asf[64][17];
  __shared__ float Bsf[16][65];
  const int bx = blockIdx.x;
  const int by = blockIdx.y;
  const int t = threadIdx.x;
  const int tc = t & 15, trw = t >> 4;
  const int m0 = by * 64, n0 = bx * 64;
  float accf[4][4] = {};
  for (int k0 = 0; k0 < 4096; k0 += 16) {
    const float* Asrc = (k0 < 2048) ? P : Dg;
    const float* Bsrc = (k0 < 2048) ? Wp : Wd;
    const int kk = k0 & 2047;
#pragma unroll
    for (int i = 0; i < 4; ++i) {
      int r = i * 16 + trw;
      Asf[r][tc] = Asrc[(size_t)(m0 + r) * 2048 + kk + tc];
    }
#pragma unroll
    for (int i = 0; i < 4; ++i) {
      int r = i * 4 + (t >> 6);
      int c = t & 63;
      Bsf[r][c] = Bsrc[(size_t)(kk + r) * 2048 + n0 + c];
    }
    __syncthreads();
#pragma unroll
    for (int k2 = 0; k2 < 16; ++k2) {
      float a[4], b[4];
#pragma unroll
      for (int i = 0; i < 4; ++i) a[i] = Asf[trw * 4 + i][k2];
#pragma unroll
      for (int j = 0; j < 4; ++j) b[j] = Bsf[k2][tc * 4 + j];
#pragma unroll
      for (int i = 0; i < 4; ++i)
#pragma unroll
        for (int j = 0; j < 4; ++j) accf[i][j] += a[i] * b[j];
    }
    __syncthreads();
  }
#pragma unroll
  for (int i = 0; i < 4; ++i)
#pragma unroll
    for (int j = 0; j < 4; ++j) {
      float v = accf[i][j] * 0.5f;
      size_t o = (size_t)(m0 + trw * 4 + i) * 4096 + n0 + tc * 4 + j;
      out[o] = v;
      out[o + 2048] = v;
    }
}

extern "C" void kernel_launch(void* const* d_in, const int* in_sizes, int n_in,
                              void* d_out, int out_size, void* d_ws, size_t ws_size,
                              hipStream_t stream) {
  // setup_inputs order: protein, drug, mask_prot, mask_drug,
  //                     Wq_p, Wk_p, Wv_p, Wq_d, Wk_d, Wv_d
  const float* protein = (const float*)d_in[0];
  const float* drug    = (const float*)d_in[1];
  const float* Wv_p    = (const float*)d_in[6];
  const float* Wv_d    = (const float*)d_in[9];
  float* out = (float*)d_out;

  const size_t wt_bytes = (size_t)N_DIM * K_DIM * sizeof(unsigned short);  // 16.8 MB

  if (ws_size >= wt_bytes) {
    unsigned short* Wt = (unsigned short*)d_ws;
    prep_wt<<<dim3(128, 64), dim3(32, 8), 0, stream>>>(Wv_p, Wv_d, Wt);
    gemm8<<<512, 512, 0, stream>>>(protein, drug, Wt, out);
  } else {
    gemm_fallback<<<dim3(32, 256), 256, 0, stream>>>(protein, drug, Wv_p, Wv_d, out);
  }
}

// Round 8
// 754.637 us; speedup vs baseline: 1.2565x; 1.2565x over previous
//
#include <hip/hip_runtime.h>
#include <stdint.h>

// CAN_Layer reduces exactly to: out[:, :2048] = out[:, 2048:] =
//   0.5 * (protein @ Wv_p + drug @ Wv_d)
// (seq-len 1 -> softmax over singleton axis == 1 -> attention = identity on V).
//
// Pipeline:
//   Pass 1a: cast+transpose Wv_p/Wv_d -> Wt bf16 [2048][4096] (B^T layout).
//   Pass 1b: cast protein|drug -> Abf bf16 [16384][4096].
//   Pass 2:  gemm8 — 256x256 tile, BK=64, 8 waves (2x4), ONE sync point per
//            K-tile: 64 MFMA(t) interleaved with 24 ds_reads R(t+1) that
//            refill IN-PLACE the registers MFMA(t) just consumed.
//
// R8 fix vs R7 (failed, absmax 0.297): cross-wave race at the prologue->loop
// seam. Steady state protects R(tt+1) reads against S(tt+3) overwrites via
// per-wave LGW0 THEN BAR (no wave stages until all waves drained reads).
// The prologue's R(0) reads had no such fence before tt=0's S(2) stage ->
// a fast wave's staged data could land over a slow wave's pending reads.
// Fix: LGW0(); BAR(); between prologue reads and the main loop.

typedef __attribute__((ext_vector_type(8))) short short8;
typedef __attribute__((ext_vector_type(4))) float float4v;
typedef __attribute__((ext_vector_type(2))) unsigned int uint2v;

typedef const __attribute__((address_space(1))) unsigned int* gp_t;
typedef __attribute__((address_space(3))) unsigned int* lp_t;

#define M_DIM 16384
#define N_DIM 2048
#define K_DIM 4096
#define OUT_LD 4096

static __device__ __forceinline__ unsigned int pack_bf16x2(float x, float y) {
  union { float f; unsigned int u; } a, b;
  a.f = x; b.f = y;
  unsigned int ua = a.u + 0x8000u;
  unsigned int ub = b.u + 0x8000u;
  return __builtin_amdgcn_perm(ub, ua, 0x07060302u);
}

static __device__ __forceinline__ unsigned short f2bf(float x) {
  union { float f; unsigned int u; } a; a.f = x;
  return (unsigned short)((a.u + 0x8000u) >> 16);
}

// ---- Pass 1a: Wt[n][k] = bf16(W[k][n]), W = Wv_p (k<2048) else Wv_d ----
__global__ __launch_bounds__(256)
void prep_wt(const float* __restrict__ Wp, const float* __restrict__ Wd,
             unsigned short* __restrict__ Wt) {
  __shared__ float tile[32][33];
  const int k0 = blockIdx.x * 32;
  const int n0 = blockIdx.y * 32;
  const int tx = threadIdx.x;
  const int ty = threadIdx.y;
  const float* W = (k0 < 2048) ? Wp : Wd;
  const int kk0 = (k0 < 2048) ? k0 : k0 - 2048;
#pragma unroll
  for (int i = 0; i < 4; ++i) {
    int r = ty * 4 + i;
    tile[r][tx] = W[(size_t)(kk0 + r) * 2048 + n0 + tx];
  }
  __syncthreads();
#pragma unroll
  for (int i = 0; i < 4; ++i) {
    int r = ty * 4 + i;
    Wt[(size_t)(n0 + r) * (size_t)K_DIM + k0 + tx] = f2bf(tile[tx][r]);
  }
}

// ---- Pass 1b: Abf[m][k] = bf16([protein | drug][m][k]) ----
__global__ __launch_bounds__(256)
void cast_a(const float* __restrict__ P, const float* __restrict__ Dg,
            unsigned int* __restrict__ Abf) {
  int idx = blockIdx.x * 256 + threadIdx.x;
  int row = idx >> 10;
  int j = (idx & 1023) << 2;
  const float* src = (j < 2048) ? (P + (size_t)row * 2048 + j)
                                : (Dg + (size_t)row * 2048 + (j - 2048));
  float4v v = *(const float4v*)src;
  uint2v o;
  o.x = pack_bf16x2(v.x, v.y);
  o.y = pack_bf16x2(v.z, v.w);
  *(uint2v*)(Abf + (size_t)row * 2048 + (j >> 1)) = o;
}

// =====================================================================
// Pass 2 ledger (tile t, buf b=t&1, nb=b^1; one sync per tile):
//  body(t): stage S(t+2)->buf b (8 gll) | 64 MFMA(t) on CUR regs,
//           in-place refill R(t+1)<-buf nb woven between MFMA groups |
//           VMW(0) LGW0 BAR.
//  Cross-wave safety (all seams): a region is overwritten only after a
//  barrier whose entry required EVERY wave to drain its reads of that
//  region (per-wave LGW0 precedes each BAR). Staged data is read only
//  after a barrier whose entry required every wave's VMW(0).
//  Prologue: S(0),S(1) (16 gll); VMW(8) retires S(0); BAR; read R(0);
//            LGW0; BAR   <- R8 fix: fences R(0) against tt=0's S(2).
//  Tail: t=0..61 full body (stages tiles 2..63); t=62 MFMA+R(63); t=63
//        MFMA only; C-write.
// =====================================================================

#define VMW(N) asm volatile("s_waitcnt vmcnt(" #N ")" ::: "memory")
#define LGW0() asm volatile("s_waitcnt lgkmcnt(0)" ::: "memory")
#define BAR() __builtin_amdgcn_s_barrier()
#define SP1 __builtin_amdgcn_s_setprio(1);
#define SP0 __builtin_amdgcn_s_setprio(0);

__global__ __launch_bounds__(512, 1)
void gemm8(const unsigned short* __restrict__ Abf,
           const unsigned short* __restrict__ Wt,
           float* __restrict__ out) {
  __shared__ unsigned short As[2][256 * 64];  // 64 KB
  __shared__ unsigned short Bs[2][256 * 64];  // 64 KB

  const int t = threadIdx.x;
  const int w = t >> 6, l = t & 63;
  const int wm = w >> 2, wn = w & 3;          // 2x4 wave grid
  const int lr = l & 15, q16 = l >> 4, xr = lr & 7;

  // Chunked XCD swizzle: XCD (bx&7) owns contiguous logical [x*64,(x+1)*64)
  const int bx = blockIdx.x;                  // 512 blocks
  const int logical = (bx & 7) * 64 + (bx >> 3);
  const int tn = logical & 7, tm = logical >> 3;
  const int m0 = tm << 8, n0 = tn << 8;

  // staging: row_in = t>>3, granule pos = t&7, swizzled src granule = pos^row
  const int srow = t >> 3;
  const int sk = (((t & 7) ^ (srow & 7)) << 3);
  const int brr = srow & 31;
  const int bsel = t >> 8;

  auto stage_a = [&](int buf, int k0, int h) {
#pragma unroll
    for (int sub = 0; sub < 2; ++sub) {
      const int row = m0 + sub * 128 + h * 64 + srow;
      const unsigned short* g = Abf + (size_t)row * K_DIM + (k0 + sk);
      const int ldsrow0 = sub * 128 + h * 64 + (w << 3);
      __builtin_amdgcn_global_load_lds((gp_t)(const void*)g,
                                       (lp_t)&As[buf][ldsrow0 * 64], 16, 0, 0);
    }
  };
  auto stage_b = [&](int buf, int k0, int nh) {
#pragma unroll
    for (int sub = 0; sub < 2; ++sub) {
      const int wnr = sub * 2 + bsel;
      const int ncol = n0 + wnr * 64 + nh * 32 + brr;
      const unsigned short* g = Wt + (size_t)ncol * K_DIM + (k0 + sk);
      const int ldsrow0 = wnr * 64 + nh * 32 + ((w & 3) << 3);
      __builtin_amdgcn_global_load_lds((gp_t)(const void*)g,
                                       (lp_t)&Bs[buf][ldsrow0 * 64], 16, 0, 0);
    }
  };

  float4v acc[8][4];
#pragma unroll
  for (int i = 0; i < 8; ++i)
#pragma unroll
    for (int j = 0; j < 4; ++j)
      acc[i][j] = (float4v){0.f, 0.f, 0.f, 0.f};

  const int aoff = (wm * 128 + lr) * 64;
  const int boff = (wn * 64 + lr) * 64;
  const int c0 = (q16 ^ xr) << 3;            // ks = 0 (swizzled granule)
  const int c1 = ((4 + q16) ^ xr) << 3;      // ks = 1

  // Full operand set for one tile: A 8 m-frags x 2 ks, B 4 n-frags x 2 ks.
  short8 aR[8][2];
  short8 bR[4][2];

  // ---- prologue: stage tiles 0,1; confirm tile 0; read R(0); fence ----
  stage_a(0, 0, 0);
  stage_a(0, 0, 1);
  stage_b(0, 0, 0);
  stage_b(0, 0, 1);
  stage_a(1, 64, 0);
  stage_b(1, 64, 0);
  stage_b(1, 64, 1);
  stage_a(1, 64, 1);
  VMW(8);                 // retires tile 0's 8, keeps tile 1's 8
  BAR();
  {
    const unsigned short* Ac = &As[0][0];
    const unsigned short* Bc = &Bs[0][0];
#pragma unroll
    for (int i = 0; i < 8; ++i) {
      aR[i][0] = *(const short8*)&Ac[aoff + i * 1024 + c0];
      aR[i][1] = *(const short8*)&Ac[aoff + i * 1024 + c1];
    }
#pragma unroll
    for (int j = 0; j < 4; ++j) {
      bR[j][0] = *(const short8*)&Bc[boff + j * 1024 + c0];
      bR[j][1] = *(const short8*)&Bc[boff + j * 1024 + c1];
    }
  }
  LGW0();                 // R8 fix: every wave's R(0) reads drained...
  BAR();                  // ...before ANY wave may stage S(2) into buf0

  // tile body: MFMA(t) on CUR regs, in-place refill from AcN/BcN (tile t+1)
  auto tile_mfma = [&](const unsigned short* AcN, const unsigned short* BcN,
                       bool doread) {
    SP1
#pragma unroll
    for (int ks = 0; ks < 2; ++ks) {
      const int cks = ks ? c1 : c0;
#pragma unroll
      for (int i = 0; i < 8; ++i) {
#pragma unroll
        for (int j = 0; j < 4; ++j)
          acc[i][j] = __builtin_amdgcn_mfma_f32_16x16x32_bf16(
              aR[i][ks], bR[j][ks], acc[i][j], 0, 0, 0);
        if (doread)
          aR[i][ks] = *(const short8*)&AcN[aoff + i * 1024 + cks];
      }
      if (doread) {
#pragma unroll
        for (int j = 0; j < 4; ++j)
          bR[j][ks] = *(const short8*)&BcN[boff + j * 1024 + cks];
      }
    }
    SP0
  };

  // ---- main loop: tiles 0..61, full body ----
  for (int tt = 0; tt < 62; ++tt) {
    const int buf = tt & 1;
    const int k2 = tt * 64 + 128;  // tile tt+2
    // stage S(tt+2) -> buf (safe: all waves' R(tt) reads fenced by prior BAR)
    stage_a(buf, k2, 0);
    stage_a(buf, k2, 1);
    stage_b(buf, k2, 0);
    stage_b(buf, k2, 1);
    // MFMA(tt) with woven in-place refill R(tt+1) from buf^1
    tile_mfma(&As[buf ^ 1][0], &Bs[buf ^ 1][0], true);
    VMW(0);   // drains S(tt+2) (issued ~2400cyc ago) + anything older
    LGW0();   // drains this wave's R(tt+1) reads
    BAR();    // publishes both; no wave proceeds until all drained
  }

  // ---- t=62: MFMA(62) + read R(63) from buf1 (staged t=61, drained+BAR'd)
  tile_mfma(&As[1][0], &Bs[1][0], true);
  // ---- t=63: MFMA only (no further LDS activity; compiler orders lgkm)
  tile_mfma(nullptr, nullptr, false);

  // ---- C write: col = lane&15, row = (lane>>4)*4 + reg; both output halves
  const int rbase = m0 + wm * 128 + q16 * 4;
  const int cbase = n0 + wn * 64 + lr;
#pragma unroll
  for (int f = 0; f < 8; ++f)
#pragma unroll
    for (int j = 0; j < 4; ++j) {
      const int row = rbase + f * 16;
      const int col = cbase + j * 16;
#pragma unroll
      for (int r = 0; r < 4; ++r) {
        float v = acc[f][j][r] * 0.5f;
        size_t o = (size_t)(row + r) * (size_t)OUT_LD + col;
        out[o] = v;
        out[o + N_DIM] = v;
      }
    }
}

// ---- mid fallback (ws holds Wt only): fp32-A m97-style GEMM ----
__global__ __launch_bounds__(256)
void gemm_k(const float* __restrict__ Ap, const float* __restrict__ Ad,
            const unsigned short* __restrict__ Wt,
            float* __restrict__ out) {
  __shared__ unsigned short As[128 * 64];
  __shared__ unsigned short Bsm[128 * 64];

  const int t = threadIdx.x;
  const int bx = blockIdx.x;
  const int tn = bx & 15, tm = bx >> 4;
  const int m0 = tm << 7, n0 = tn << 7;
  const int w = t >> 6, l = t & 63;
  const int wmm = w & 1, wnn = w >> 1;
  const int lr = l & 15, q = l >> 4;

  const int rB = t >> 3;
  const int kB = (t & 7) * 8;

  float4v acc[4][4];
#pragma unroll
  for (int i = 0; i < 4; ++i)
#pragma unroll
    for (int j = 0; j < 4; ++j)
      acc[i][j] = (float4v){0.f, 0.f, 0.f, 0.f};

  for (int k0 = 0; k0 < K_DIM; k0 += 64) {
#pragma unroll
    for (int i = 0; i < 4; ++i) {
      const unsigned short* g =
          Wt + (size_t)(n0 + i * 32 + rB) * (size_t)K_DIM + (k0 + kB);
      __builtin_amdgcn_global_load_lds((gp_t)(const void*)g,
                                       (lp_t)&Bsm[i * 2048 + w * 512], 16, 0, 0);
    }
    {
      const float* base;
      int kk;
      if (k0 < 2048) { base = Ap; kk = k0; } else { base = Ad; kk = k0 - 2048; }
      const int rA = t >> 4;
      const int cA = (t & 15) * 4;
#pragma unroll
      for (int i = 0; i < 8; ++i) {
        int m = i * 16 + rA;
        float4v v = *(const float4v*)(base + (size_t)(m0 + m) * 2048 + kk + cA);
        uint2v o;
        o.x = pack_bf16x2(v.x, v.y);
        o.y = pack_bf16x2(v.z, v.w);
        *(uint2v*)&As[m * 64 + cA] = o;
      }
    }
    __syncthreads();

#pragma unroll
    for (int ks = 0; ks < 2; ++ks) {
      short8 a2[4], b2[4];
#pragma unroll
      for (int i = 0; i < 4; ++i) {
        a2[i] = *(const short8*)&As[(wmm * 64 + i * 16 + lr) * 64 + ks * 32 + q * 8];
        b2[i] = *(const short8*)&Bsm[(wnn * 64 + i * 16 + lr) * 64 + ks * 32 + q * 8];
      }
#pragma unroll
      for (int i = 0; i < 4; ++i)
#pragma unroll
        for (int j = 0; j < 4; ++j)
          acc[i][j] = __builtin_amdgcn_mfma_f32_16x16x32_bf16(a2[i], b2[j],
                                                              acc[i][j], 0, 0, 0);
    }
    __syncthreads();
  }

#pragma unroll
  for (int i = 0; i < 4; ++i) {
    const int r0 = m0 + wmm * 64 + i * 16 + q * 4;
#pragma unroll
    for (int j = 0; j < 4; ++j) {
      const int c = n0 + wnn * 64 + j * 16 + lr;
#pragma unroll
      for (int r = 0; r < 4; ++r) {
        float v = acc[i][j][r] * 0.5f;
        size_t o = (size_t)(r0 + r) * (size_t)OUT_LD + c;
        out[o] = v;
        out[o + 2048] = v;
      }
    }
  }
}

// ---- insurance fallback (no usable ws): fp32 LDS-tiled vector GEMM ----
__global__ __launch_bounds__(256)
void gemm_fallback(const float* __restrict__ P, const float* __restrict__ Dg,
                   const float* __restrict__ Wp, const float* __restrict__ Wd,
                   float* __restrict__ out) {
  __shared__ float Asf[64][17];
  __shared__ float Bsf[16][65];
  const int bx = blockIdx.x;
  const int by = blockIdx.y;
  const int t = threadIdx.x;
  const int tc = t & 15, trw = t >> 4;
  const int m0 = by * 64, n0 = bx * 64;
  float accf[4][4] = {};
  for (int k0 = 0; k0 < 4096; k0 += 16) {
    const float* Asrc = (k0 < 2048) ? P : Dg;
    const float* Bsrc = (k0 < 2048) ? Wp : Wd;
    const int kk = k0 & 2047;
#pragma unroll
    for (int i = 0; i < 4; ++i) {
      int r = i * 16 + trw;
      Asf[r][tc] = Asrc[(size_t)(m0 + r) * 2048 + kk + tc];
    }
#pragma unroll
    for (int i = 0; i < 4; ++i) {
      int r = i * 4 + (t >> 6);
      int c = t & 63;
      Bsf[r][c] = Bsrc[(size_t)(kk + r) * 2048 + n0 + c];
    }
    __syncthreads();
#pragma unroll
    for (int k2 = 0; k2 < 16; ++k2) {
      float a[4], b[4];
#pragma unroll
      for (int i = 0; i < 4; ++i) a[i] = Asf[trw * 4 + i][k2];
#pragma unroll
      for (int j = 0; j < 4; ++j) b[j] = Bsf[k2][tc * 4 + j];
#pragma unroll
      for (int i = 0; i < 4; ++i)
#pragma unroll
        for (int j = 0; j < 4; ++j) accf[i][j] += a[i] * b[j];
    }
    __syncthreads();
  }
#pragma unroll
  for (int i = 0; i < 4; ++i)
#pragma unroll
    for (int j = 0; j < 4; ++j) {
      float v = accf[i][j] * 0.5f;
      size_t o = (size_t)(m0 + trw * 4 + i) * 4096 + n0 + tc * 4 + j;
      out[o] = v;
      out[o + 2048] = v;
    }
}

extern "C" void kernel_launch(void* const* d_in, const int* in_sizes, int n_in,
                              void* d_out, int out_size, void* d_ws, size_t ws_size,
                              hipStream_t stream) {
  // setup_inputs order: protein, drug, mask_prot, mask_drug,
  //                     Wq_p, Wk_p, Wv_p, Wq_d, Wk_d, Wv_d
  const float* protein = (const float*)d_in[0];
  const float* drug    = (const float*)d_in[1];
  const float* Wv_p    = (const float*)d_in[6];
  const float* Wv_d    = (const float*)d_in[9];
  float* out = (float*)d_out;

  const size_t wt_bytes = (size_t)N_DIM * K_DIM * sizeof(unsigned short);  // 16.8 MB
  const size_t a_bytes  = (size_t)M_DIM * K_DIM * sizeof(unsigned short);  // 134 MB

  if (ws_size >= wt_bytes) {
    unsigned short* Wt = (unsigned short*)d_ws;
    prep_wt<<<dim3(128, 64), dim3(32, 8), 0, stream>>>(Wv_p, Wv_d, Wt);
    if (ws_size >= wt_bytes + a_bytes) {
      unsigned int* Abf = (unsigned int*)((char*)d_ws + wt_bytes);
      cast_a<<<65536, 256, 0, stream>>>(protein, drug, Abf);
      gemm8<<<512, 512, 0, stream>>>((const unsigned short*)Abf, Wt, out);
    } else {
      gemm_k<<<2048, 256, 0, stream>>>(protein, drug, Wt, out);
    }
  } else {
    gemm_fallback<<<dim3(32, 256), 256, 0, stream>>>(protein, drug, Wv_p, Wv_d, out);
  }
}